// Round 8
// baseline (403.535 us; speedup 1.0000x reference)
//
#include <hip/hip_runtime.h>

#define N 4096
#define D 1024
#define EPSF 1e-6f

// ===== AMPLIFICATION PROBE ROUND =====
// Each kernel body wrapped in an idempotent repeat loop so every kernel's
// dispatch exceeds the 41us fillBuffer floor and appears in top-5.
// Per-kernel single cost = dispatch_dur / REP_*.
#define REP_PREP  24
#define REP_MASK  20
#define REP_PACK  16
#define REP_GEMM  10
#define REP_WRITE 8

typedef _Float16 f16;
typedef f16 f16x8 __attribute__((ext_vector_type(8)));
typedef float f32x4 __attribute__((ext_vector_type(4)));
typedef unsigned long long u64;

#define PLANE ((size_t)2048 * 1024)  // f16 elements per packed plane

struct WS {
  int n_A, mid, n2, n_B, n_resid, pad[3];
  float a[N];
  float diag[N];
  int A1idx[N];
  int A2idx[N];
  int Bidx[N];
  int matches[N];
  int residIdx[N];
  u64 bestKey[2048];
};

__device__ __forceinline__ u64 packKey(float v, int j) {
  unsigned u = __float_as_uint(v);
  unsigned m = (u & 0x80000000u) ? ~u : (u | 0x80000000u);
  return ((u64)m << 32) | (unsigned)(~(unsigned)j);
}

// row means of x + attn diagonal gather
__global__ __launch_bounds__(256) void k_prep(const float* __restrict__ x,
                                              const float* __restrict__ attn, WS* ws) {
  int row = blockIdx.x;
  int t = threadIdx.x;
  __shared__ float w[4];
  #pragma unroll 1
  for (int rep = 0; rep < REP_PREP; rep++) {
    float4 v = ((const float4*)(x + (size_t)row * D))[t];
    float sm = v.x + v.y + v.z + v.w;
    for (int o = 32; o; o >>= 1) sm += __shfl_down(sm, o, 64);
    if ((t & 63) == 0) w[t >> 6] = sm;
    __syncthreads();
    if (t == 0) {
      ws->a[row] = (w[0] + w[1] + w[2] + w[3]) * (1.0f / D);
      ws->diag[row] = attn[(size_t)row * N + row];
    }
    __syncthreads();
  }
}

// fused: stats -> Il -> stats -> s -> radix median -> mask + compaction
__global__ __launch_bounds__(1024) void k_mask(WS* ws) {
  __shared__ double dred[16], dred2[16];
  __shared__ float bcast[2];
  __shared__ int hist[256];
  __shared__ int wsum[16];
  __shared__ unsigned sPrefix;
  __shared__ int sRank;
  int tid = threadIdx.x;
  int lane = tid & 63, wv = tid >> 6;

  #pragma unroll 1
  for (int rep = 0; rep < REP_MASK; rep++) {
    __syncthreads();
    ws->bestKey[tid] = 0ull;
    ws->bestKey[tid + 1024] = 0ull;

    float av[4];
    double s = 0.0, s2 = 0.0;
    #pragma unroll
    for (int q = 0; q < 4; q++) {
      float f = ws->a[tid * 4 + q];
      av[q] = f; s += f; s2 += (double)f * f;
    }
    for (int o = 32; o; o >>= 1) { s += __shfl_down(s, o, 64); s2 += __shfl_down(s2, o, 64); }
    if (lane == 0) { dred[wv] = s; dred2[wv] = s2; }
    __syncthreads();
    if (tid == 0) {
      double t1 = 0, t2 = 0;
      for (int i = 0; i < 16; i++) { t1 += dred[i]; t2 += dred2[i]; }
      bcast[0] = (float)(t1 / N);
      bcast[1] = (float)sqrt((t2 - t1 * t1 / N) / (N - 1));
    }
    __syncthreads();
    float meanA = bcast[0], stdA = bcast[1];

    float il[4];
    s = 0.0; s2 = 0.0;
    #pragma unroll
    for (int q = 0; q < 4; q++) {
      int i = tid * 4 + q;
      float z = (av[q] - meanA) / (stdA + EPSF);
      float I = z * z * ws->diag[i];
      il[q] = I; s += I; s2 += (double)I * I;
    }
    for (int o = 32; o; o >>= 1) { s += __shfl_down(s, o, 64); s2 += __shfl_down(s2, o, 64); }
    __syncthreads();
    if (lane == 0) { dred[wv] = s; dred2[wv] = s2; }
    __syncthreads();
    if (tid == 0) {
      double t1 = 0, t2 = 0;
      for (int i = 0; i < 16; i++) { t1 += dred[i]; t2 += dred2[i]; }
      bcast[0] = (float)(t1 / N);
      bcast[1] = (float)sqrt((t2 - t1 * t1 / N) / (N - 1));
      sPrefix = 0u; sRank = (N - 1) / 2;
    }
    __syncthreads();
    float meanI = bcast[0], stdI = bcast[1];

    float sv[4]; unsigned ab[4];
    #pragma unroll
    for (int q = 0; q < 4; q++) {
      float sval = (il[q] - meanI) / (stdI + EPSF);
      sv[q] = sval;
      ab[q] = __float_as_uint(fabsf(sval));
    }

    for (int p = 3; p >= 0; p--) {
      if (tid < 256) hist[tid] = 0;
      __syncthreads();
      unsigned pre = sPrefix;
      int rk = sRank;
      int sh = p * 8;
      unsigned mHi = (p == 3) ? 0u : (0xFFFFFFFFu << (sh + 8));
      #pragma unroll
      for (int q = 0; q < 4; q++)
        if ((ab[q] & mHi) == pre) atomicAdd(&hist[(ab[q] >> sh) & 255], 1);
      __syncthreads();
      int v = (tid < 256) ? hist[tid] : 0;
      int inc = v;
      #pragma unroll
      for (int o = 1; o < 64; o <<= 1) { int u = __shfl_up(inc, o, 64); if (lane >= o) inc += u; }
      if (lane == 63) wsum[wv] = inc;
      __syncthreads();
      if (tid < 16) {
        int t = wsum[tid];
        #pragma unroll
        for (int o = 1; o < 16; o <<= 1) { int u = __shfl_up(t, o, 64); if (tid >= o) t += u; }
        wsum[tid] = t;
      }
      __syncthreads();
      int incl = (wv ? wsum[wv - 1] : 0) + inc;
      int E = incl - v;
      if (tid < 256 && v && rk >= E && rk < E + v) {
        sPrefix = pre | ((unsigned)tid << sh);
        sRank = rk - E;
      }
      __syncthreads();
    }
    float med = __uint_as_float(sPrefix);

    int msk[4], loc[4]; int tot = 0;
    #pragma unroll
    for (int q = 0; q < 4; q++) {
      bool m = fabsf(sv[q]) > med;
      msk[q] = m; loc[q] = tot; tot += (int)m;
    }
    int inc = tot;
    #pragma unroll
    for (int o = 1; o < 64; o <<= 1) { int u = __shfl_up(inc, o, 64); if (lane >= o) inc += u; }
    if (lane == 63) wsum[wv] = inc;
    __syncthreads();
    if (tid < 16) {
      int t = wsum[tid];
      #pragma unroll
      for (int o = 1; o < 16; o <<= 1) { int u = __shfl_up(t, o, 64); if (tid >= o) t += u; }
      wsum[tid] = t;
    }
    __syncthreads();
    int nA = wsum[15];
    int base = (wv ? wsum[wv - 1] : 0) + inc - tot;
    int midl = nA >> 1;
    #pragma unroll
    for (int q = 0; q < 4; q++) {
      int i = tid * 4 + q;
      int r = base + loc[q];
      if (msk[q]) {
        if (r < midl) ws->A1idx[r] = i; else ws->A2idx[r - midl] = i;
      } else {
        ws->Bidx[i - r] = i;
      }
    }
    if (tid == 0) { ws->n_A = nA; ws->mid = midl; ws->n2 = nA - midl; ws->n_B = N - nA; }
  }
}

// gather selected rows -> tiled swizzled f16 hi/lo planes
__global__ __launch_bounds__(128) void k_pack(const float* __restrict__ x,
                                              f16* __restrict__ PAhi, f16* __restrict__ PAlo,
                                              f16* __restrict__ PBhi, f16* __restrict__ PBlo,
                                              WS* ws) {
  int b = blockIdx.x, t = threadIdx.x;
  const float* src;
  f16 *dh, *dl;
  int j;
  if (b < 2048) {
    if (b >= ws->mid) return;
    j = b;
    src = x + (size_t)ws->A1idx[b] * D;
    dh = PAhi; dl = PAlo;
  } else {
    j = b - 2048;
    if (j >= ws->n2) return;
    src = x + (size_t)ws->A2idx[j] * D;
    dh = PBhi; dl = PBlo;
  }
  int rt = j >> 6, rl = j & 63;
  int kt = t >> 3, gl = t & 7;
  size_t off = ((size_t)(rt * 16 + kt) << 12) + rl * 64 + ((gl ^ (rl & 7)) * 8);
  #pragma unroll 1
  for (int rep = 0; rep < REP_PACK; rep++) {
    float4 v0 = ((const float4*)src)[t * 2];
    float4 v1 = ((const float4*)src)[t * 2 + 1];
    float vv[8] = {v0.x, v0.y, v0.z, v0.w, v1.x, v1.y, v1.z, v1.w};
    f16x8 h, l;
    #pragma unroll
    for (int q = 0; q < 8; q++) {
      f16 hq = (f16)vv[q];
      h[q] = hq;
      l[q] = (f16)(vv[q] - (float)hq);
    }
    *(f16x8*)(dh + off) = h;
    *(f16x8*)(dl + off) = l;
  }
}

// f16x3 MFMA sim-GEMM on tiled packed planes + per-row argmax
__global__ __launch_bounds__(256) void k_gemm(const f16* __restrict__ PAhi,
                                              const f16* __restrict__ PAlo,
                                              const f16* __restrict__ PBhi,
                                              const f16* __restrict__ PBlo, WS* ws) {
  const int mid = ws->mid, n2 = ws->n2;
  int L = blockIdx.x;
  int local = L >> 3;
  int bj = ((L & 7) << 1) | (local >> 4);
  int bi = local & 15;
  if (bi * 64 >= mid || bj * 64 >= n2) return;

  __shared__ f16 lds[2][4][64 * 64];

  const int tid = threadIdx.x;
  const int lane = tid & 63;
  const int wid = tid >> 6;
  const int wr = wid >> 1, wc = wid & 1;

  const f16* plane = (wid == 0) ? PAhi : (wid == 1) ? PAlo : (wid == 2) ? PBhi : PBlo;
  const int ptile = (wid < 2) ? bi : bj;

  f16x8 pr[8];
  auto LOAD = [&](int t) {
    const f16* tb = plane + ((size_t)((ptile << 4) + t) << 12);
    #pragma unroll
    for (int i = 0; i < 8; i++) pr[i] = *(const f16x8*)(tb + i * 512 + lane * 8);
  };
  auto STORE = [&](int buf) {
    #pragma unroll
    for (int i = 0; i < 8; i++) *(f16x8*)&lds[buf][wid][i * 512 + lane * 8] = pr[i];
  };

  const int colg = lane & 15, rowg = lane >> 4;
  const int ma0 = wr * 32 + colg, ma1 = ma0 + 16;
  const int mb0 = wc * 32 + colg, mb1 = mb0 + 16;

#define FRAG(buf, t4, row, g) \
  (*(const f16x8*)&lds[buf][t4][(row) * 64 + ((((g) ^ ((row) & 7))) * 8)])

  #pragma unroll 1
  for (int rep = 0; rep < REP_GEMM; rep++) {
    f32x4 zero = {0.f, 0.f, 0.f, 0.f};
    f32x4 acc[2][2];
    acc[0][0] = zero; acc[0][1] = zero; acc[1][0] = zero; acc[1][1] = zero;

    LOAD(0);
    STORE(0);
    __syncthreads();
    #pragma unroll 1
    for (int t16 = 0; t16 < 16; t16++) {
      int buf = t16 & 1;
      if (t16 < 15) LOAD(t16 + 1);
      #pragma unroll
      for (int ks = 0; ks < 2; ks++) {
        int gk = ks * 4 + rowg;
        f16x8 ah0 = FRAG(buf, 0, ma0, gk), ah1 = FRAG(buf, 0, ma1, gk);
        f16x8 al0 = FRAG(buf, 1, ma0, gk), al1 = FRAG(buf, 1, ma1, gk);
        f16x8 bh0 = FRAG(buf, 2, mb0, gk), bh1 = FRAG(buf, 2, mb1, gk);
        f16x8 bl0 = FRAG(buf, 3, mb0, gk), bl1 = FRAG(buf, 3, mb1, gk);
        acc[0][0] = __builtin_amdgcn_mfma_f32_16x16x32_f16(ah0, bh0, acc[0][0], 0, 0, 0);
        acc[0][0] = __builtin_amdgcn_mfma_f32_16x16x32_f16(ah0, bl0, acc[0][0], 0, 0, 0);
        acc[0][0] = __builtin_amdgcn_mfma_f32_16x16x32_f16(al0, bh0, acc[0][0], 0, 0, 0);
        acc[0][1] = __builtin_amdgcn_mfma_f32_16x16x32_f16(ah0, bh1, acc[0][1], 0, 0, 0);
        acc[0][1] = __builtin_amdgcn_mfma_f32_16x16x32_f16(ah0, bl1, acc[0][1], 0, 0, 0);
        acc[0][1] = __builtin_amdgcn_mfma_f32_16x16x32_f16(al0, bh1, acc[0][1], 0, 0, 0);
        acc[1][0] = __builtin_amdgcn_mfma_f32_16x16x32_f16(ah1, bh0, acc[1][0], 0, 0, 0);
        acc[1][0] = __builtin_amdgcn_mfma_f32_16x16x32_f16(ah1, bl0, acc[1][0], 0, 0, 0);
        acc[1][0] = __builtin_amdgcn_mfma_f32_16x16x32_f16(al1, bh0, acc[1][0], 0, 0, 0);
        acc[1][1] = __builtin_amdgcn_mfma_f32_16x16x32_f16(ah1, bh1, acc[1][1], 0, 0, 0);
        acc[1][1] = __builtin_amdgcn_mfma_f32_16x16x32_f16(ah1, bl1, acc[1][1], 0, 0, 0);
        acc[1][1] = __builtin_amdgcn_mfma_f32_16x16x32_f16(al1, bh1, acc[1][1], 0, 0, 0);
      }
      if (t16 < 15) {
        __syncthreads();
        STORE(buf ^ 1);
        __syncthreads();
      }
    }

    #pragma unroll
    for (int mi = 0; mi < 2; mi++) {
      #pragma unroll
      for (int i = 0; i < 4; i++) {
        int grow = bi * 64 + wr * 32 + mi * 16 + rowg * 4 + i;
        u64 key = 0;
        #pragma unroll
        for (int ni = 0; ni < 2; ni++) {
          int gcol = bj * 64 + wc * 32 + ni * 16 + colg;
          if (gcol < n2) {
            u64 k2 = packKey(acc[mi][ni][i], gcol);
            if (k2 > key) key = k2;
          }
        }
        #pragma unroll
        for (int m = 8; m; m >>= 1) {
          u64 o = (u64)__shfl_xor((long long)key, m, 64);
          if (o > key) key = o;
        }
        if (colg == 0 && grow < mid && key) atomicMax(&ws->bestKey[grow], key);
      }
    }
  }
#undef FRAG
}

// decode matches + residual compaction (unamplified)
__global__ __launch_bounds__(1024) void k_match(WS* ws) {
  __shared__ int flag[N];
  __shared__ int wsum[16];
  int tid = threadIdx.x;
  int lane = tid & 63, wv = tid >> 6;
  int mid = ws->mid, n2 = ws->n2;
  #pragma unroll
  for (int q = 0; q < 4; q++) flag[tid * 4 + q] = 0;
  __syncthreads();
  #pragma unroll
  for (int q = 0; q < 2; q++) {
    int r = tid + q * 1024;
    if (r < mid) {
      int j = (int)(~(unsigned)(ws->bestKey[r] & 0xffffffffull));
      ws->matches[r] = j;
      flag[j] = 1;
    }
  }
  __syncthreads();
  int v[4], loc[4]; int tot = 0;
  #pragma unroll
  for (int q = 0; q < 4; q++) {
    int j = tid * 4 + q;
    bool val = (j < n2) && (flag[j] == 0);
    v[q] = val; loc[q] = tot; tot += (int)val;
  }
  int inc = tot;
  #pragma unroll
  for (int o = 1; o < 64; o <<= 1) { int u = __shfl_up(inc, o, 64); if (lane >= o) inc += u; }
  if (lane == 63) wsum[wv] = inc;
  __syncthreads();
  if (tid < 16) {
    int t = wsum[tid];
    #pragma unroll
    for (int o = 1; o < 16; o <<= 1) { int u = __shfl_up(t, o, 64); if (tid >= o) t += u; }
    wsum[tid] = t;
  }
  __syncthreads();
  int base = (wv ? wsum[wv - 1] : 0) + inc - tot;
  #pragma unroll
  for (int q = 0; q < 4; q++)
    if (v[q]) ws->residIdx[base + loc[q]] = ws->A2idx[tid * 4 + q];
  if (tid == 0) ws->n_resid = wsum[15];
}

// one block per output row (out rows [0,N), residual rows [N,2N))
__global__ __launch_bounds__(256) void k_write(const float* __restrict__ x,
                                               float* __restrict__ out, WS* ws) {
  int r = blockIdx.x;
  int t = threadIdx.x;
  #pragma unroll 1
  for (int rep = 0; rep < REP_WRITE; rep++) {
    int n_B = ws->n_B, mid = ws->mid, n_resid = ws->n_resid;
    float4 res = make_float4(0.f, 0.f, 0.f, 0.f);
    if (r < N) {
      if (r < n_B) {
        res = ((const float4*)(x + (size_t)ws->Bidx[r] * D))[t];
      } else if (r < n_B + mid) {
        int m = r - n_B;
        float4 v1 = ((const float4*)(x + (size_t)ws->A1idx[m] * D))[t];
        float4 v2 = ((const float4*)(x + (size_t)ws->A2idx[ws->matches[m]] * D))[t];
        res = make_float4(0.5f * (v1.x + v2.x), 0.5f * (v1.y + v2.y),
                          0.5f * (v1.z + v2.z), 0.5f * (v1.w + v2.w));
      }
    } else {
      int k = r - N;
      if (k < n_resid) {
        res = ((const float4*)(x + (size_t)ws->residIdx[k] * D))[t];
      }
    }
    ((float4*)(out + (size_t)r * D))[t] = res;
  }
}

extern "C" void kernel_launch(void* const* d_in, const int* in_sizes, int n_in,
                              void* d_out, int out_size, void* d_ws, size_t ws_size,
                              hipStream_t stream) {
  const float* x = (const float*)d_in[0];
  const float* attn = (const float*)d_in[1];
  float* out = (float*)d_out;
  WS* ws = (WS*)d_ws;
  f16* PAhi = (f16*)d_out;
  f16* PAlo = PAhi + PLANE;
  f16* PBhi = PAlo + PLANE;
  f16* PBlo = PBhi + PLANE;

  k_prep<<<N, 256, 0, stream>>>(x, attn, ws);
  k_mask<<<1, 1024, 0, stream>>>(ws);
  k_pack<<<4096, 128, 0, stream>>>(x, PAhi, PAlo, PBhi, PBlo, ws);
  k_gemm<<<256, 256, 0, stream>>>(PAhi, PAlo, PBhi, PBlo, ws);
  k_match<<<1, 1024, 0, stream>>>(ws);
  k_write<<<2 * N, 256, 0, stream>>>(x, out, ws);
}

// Round 11
// 58.179 us; speedup vs baseline: 6.9361x; 6.9361x over previous
//
#include <hip/hip_runtime.h>

#define N 4096
#define D 1024
#define EPSF 1e-6f

typedef _Float16 f16;
typedef f16 f16x8 __attribute__((ext_vector_type(8)));
typedef float f32x4 __attribute__((ext_vector_type(4)));
typedef unsigned long long u64;

#define PLANE ((size_t)2048 * 1024)  // f16 elements per packed plane

struct WS {
  int n_A, mid, n2, n_B, n_resid, pad[3];
  float a[N];
  float diag[N];
  int A1idx[N];
  int A2idx[N];
  int Bidx[N];
  int matches[N];
  int residIdx[N];
  u64 bestKey[2048];
};

__device__ __forceinline__ u64 packKey(float v, int j) {
  unsigned u = __float_as_uint(v);
  unsigned m = (u & 0x80000000u) ? ~u : (u | 0x80000000u);
  return ((u64)m << 32) | (unsigned)(~(unsigned)j);
}

// ===== row means of x + attn diagonal (verbatim round 7) =====
__global__ __launch_bounds__(256) void k_prep(const float* __restrict__ x,
                                              const float* __restrict__ attn, WS* ws) {
  int row = blockIdx.x;
  int t = threadIdx.x;
  float4 v = ((const float4*)(x + (size_t)row * D))[t];
  float sm = v.x + v.y + v.z + v.w;
  for (int o = 32; o; o >>= 1) sm += __shfl_down(sm, o, 64);
  __shared__ float w[4];
  if ((t & 63) == 0) w[t >> 6] = sm;
  __syncthreads();
  if (t == 0) {
    ws->a[row] = (w[0] + w[1] + w[2] + w[3]) * (1.0f / D);
    ws->diag[row] = attn[(size_t)row * N + row];
  }
}

// ===== fused mask, SLIMMED: 256 threads (4 waves), 16 elems/thread =====
// (single isolated change this round; all I/O at kernel boundaries)
__global__ __launch_bounds__(256) void k_mask(WS* ws) {
  __shared__ double dred[4], dred2[4];
  __shared__ float bcast[2];
  __shared__ int hist[256];
  __shared__ int wsum[4];
  __shared__ unsigned sPrefix;
  __shared__ int sRank;
  int tid = threadIdx.x;
  int lane = tid & 63, wv = tid >> 6;

  // zero bestKey for gemm's atomicMax
  #pragma unroll
  for (int q = 0; q < 8; q++) ws->bestKey[tid * 8 + q] = 0ull;

  // stats of a
  float av[16];
  double s = 0.0, s2 = 0.0;
  #pragma unroll
  for (int q = 0; q < 4; q++) {
    float4 va = ((const float4*)ws->a)[tid * 4 + q];
    float f4[4] = {va.x, va.y, va.z, va.w};
    #pragma unroll
    for (int e = 0; e < 4; e++) {
      av[q * 4 + e] = f4[e];
      s += f4[e]; s2 += (double)f4[e] * f4[e];
    }
  }
  for (int o = 32; o; o >>= 1) { s += __shfl_down(s, o, 64); s2 += __shfl_down(s2, o, 64); }
  if (lane == 0) { dred[wv] = s; dred2[wv] = s2; }
  __syncthreads();
  if (tid == 0) {
    double t1 = dred[0] + dred[1] + dred[2] + dred[3];
    double t2 = dred2[0] + dred2[1] + dred2[2] + dred2[3];
    bcast[0] = (float)(t1 / N);
    bcast[1] = (float)sqrt((t2 - t1 * t1 / N) / (N - 1));
  }
  __syncthreads();
  float meanA = bcast[0], stdA = bcast[1];

  // Il = z^2 * diag + its stats
  float il[16];
  s = 0.0; s2 = 0.0;
  #pragma unroll
  for (int q = 0; q < 4; q++) {
    float4 dg = ((const float4*)ws->diag)[tid * 4 + q];
    float d4[4] = {dg.x, dg.y, dg.z, dg.w};
    #pragma unroll
    for (int e = 0; e < 4; e++) {
      float z = (av[q * 4 + e] - meanA) / (stdA + EPSF);
      float I = z * z * d4[e];
      il[q * 4 + e] = I;
      s += I; s2 += (double)I * I;
    }
  }
  for (int o = 32; o; o >>= 1) { s += __shfl_down(s, o, 64); s2 += __shfl_down(s2, o, 64); }
  __syncthreads();
  if (lane == 0) { dred[wv] = s; dred2[wv] = s2; }
  __syncthreads();
  if (tid == 0) {
    double t1 = dred[0] + dred[1] + dred[2] + dred[3];
    double t2 = dred2[0] + dred2[1] + dred2[2] + dred2[3];
    bcast[0] = (float)(t1 / N);
    bcast[1] = (float)sqrt((t2 - t1 * t1 / N) / (N - 1));
    sPrefix = 0u; sRank = (N - 1) / 2;
  }
  __syncthreads();
  float meanI = bcast[0], stdI = bcast[1];

  float sv[16]; unsigned ab[16];
  #pragma unroll
  for (int q = 0; q < 16; q++) {
    float sval = (il[q] - meanI) / (stdI + EPSF);
    sv[q] = sval;
    ab[q] = __float_as_uint(fabsf(sval));
  }

  // radix select rank-2047 of |s| bit patterns (4 passes)
  for (int p = 3; p >= 0; p--) {
    hist[tid] = 0;
    __syncthreads();
    unsigned pre = sPrefix;
    int rk = sRank;
    int sh = p * 8;
    unsigned mHi = (p == 3) ? 0u : (0xFFFFFFFFu << (sh + 8));
    #pragma unroll
    for (int q = 0; q < 16; q++)
      if ((ab[q] & mHi) == pre) atomicAdd(&hist[(ab[q] >> sh) & 255], 1);
    __syncthreads();
    int v2 = hist[tid];
    int inc = v2;
    #pragma unroll
    for (int o = 1; o < 64; o <<= 1) { int u = __shfl_up(inc, o, 64); if (lane >= o) inc += u; }
    if (lane == 63) wsum[wv] = inc;
    __syncthreads();
    if (tid == 0) { wsum[1] += wsum[0]; wsum[2] += wsum[1]; wsum[3] += wsum[2]; }
    __syncthreads();
    int incl = (wv ? wsum[wv - 1] : 0) + inc;
    int E = incl - v2;
    if (v2 && rk >= E && rk < E + v2) {
      sPrefix = pre | ((unsigned)tid << sh);
      sRank = rk - E;
    }
    __syncthreads();
  }
  float med = __uint_as_float(sPrefix);

  // mask (strict |s| > med, bit-exact) + stable compaction
  int msk[16], loc[16]; int tot = 0;
  #pragma unroll
  for (int q = 0; q < 16; q++) {
    bool m = fabsf(sv[q]) > med;
    msk[q] = m; loc[q] = tot; tot += (int)m;
  }
  int inc = tot;
  #pragma unroll
  for (int o = 1; o < 64; o <<= 1) { int u = __shfl_up(inc, o, 64); if (lane >= o) inc += u; }
  if (lane == 63) wsum[wv] = inc;
  __syncthreads();
  if (tid == 0) { wsum[1] += wsum[0]; wsum[2] += wsum[1]; wsum[3] += wsum[2]; }
  __syncthreads();
  int nA = wsum[3];
  int base = (wv ? wsum[wv - 1] : 0) + inc - tot;
  int midl = nA >> 1;
  #pragma unroll
  for (int q = 0; q < 16; q++) {
    int i = tid * 16 + q;
    int r = base + loc[q];
    if (msk[q]) {
      if (r < midl) ws->A1idx[r] = i; else ws->A2idx[r - midl] = i;
    } else {
      ws->Bidx[i - r] = i;
    }
  }
  if (tid == 0) { ws->n_A = nA; ws->mid = midl; ws->n2 = nA - midl; ws->n_B = N - nA; }
}

// ===== gather selected rows -> tiled swizzled f16 hi/lo planes (verbatim r7) =====
__global__ __launch_bounds__(128) void k_pack(const float* __restrict__ x,
                                              f16* __restrict__ PAhi, f16* __restrict__ PAlo,
                                              f16* __restrict__ PBhi, f16* __restrict__ PBlo,
                                              WS* ws) {
  int b = blockIdx.x, t = threadIdx.x;
  const float* src;
  f16 *dh, *dl;
  int j;
  if (b < 2048) {
    if (b >= ws->mid) return;
    j = b;
    src = x + (size_t)ws->A1idx[b] * D;
    dh = PAhi; dl = PAlo;
  } else {
    j = b - 2048;
    if (j >= ws->n2) return;
    src = x + (size_t)ws->A2idx[j] * D;
    dh = PBhi; dl = PBlo;
  }
  float4 v0 = ((const float4*)src)[t * 2];
  float4 v1 = ((const float4*)src)[t * 2 + 1];
  float vv[8] = {v0.x, v0.y, v0.z, v0.w, v1.x, v1.y, v1.z, v1.w};
  f16x8 h, l;
  #pragma unroll
  for (int q = 0; q < 8; q++) {
    f16 hq = (f16)vv[q];
    h[q] = hq;
    l[q] = (f16)(vv[q] - (float)hq);
  }
  int rt = j >> 6, rl = j & 63;
  int kt = t >> 3, gl = t & 7;
  size_t off = ((size_t)(rt * 16 + kt) << 12) + rl * 64 + ((gl ^ (rl & 7)) * 8);
  *(f16x8*)(dh + off) = h;
  *(f16x8*)(dl + off) = l;
}

// ===== f16x3 MFMA sim-GEMM on tiled packed planes + argmax (verbatim r7) =====
__global__ __launch_bounds__(256) void k_gemm(const f16* __restrict__ PAhi,
                                              const f16* __restrict__ PAlo,
                                              const f16* __restrict__ PBhi,
                                              const f16* __restrict__ PBlo, WS* ws) {
  const int mid = ws->mid, n2 = ws->n2;
  int L = blockIdx.x;
  int local = L >> 3;
  int bj = ((L & 7) << 1) | (local >> 4);
  int bi = local & 15;
  if (bi * 64 >= mid || bj * 64 >= n2) return;

  __shared__ f16 lds[2][4][64 * 64];

  const int tid = threadIdx.x;
  const int lane = tid & 63;
  const int wid = tid >> 6;
  const int wr = wid >> 1, wc = wid & 1;

  const f16* plane = (wid == 0) ? PAhi : (wid == 1) ? PAlo : (wid == 2) ? PBhi : PBlo;
  const int ptile = (wid < 2) ? bi : bj;

  f16x8 pr[8];
  auto LOAD = [&](int t) {
    const f16* tb = plane + ((size_t)((ptile << 4) + t) << 12);
    #pragma unroll
    for (int i = 0; i < 8; i++) pr[i] = *(const f16x8*)(tb + i * 512 + lane * 8);
  };
  auto STORE = [&](int buf) {
    #pragma unroll
    for (int i = 0; i < 8; i++) *(f16x8*)&lds[buf][wid][i * 512 + lane * 8] = pr[i];
  };

  const int colg = lane & 15, rowg = lane >> 4;
  const int ma0 = wr * 32 + colg, ma1 = ma0 + 16;
  const int mb0 = wc * 32 + colg, mb1 = mb0 + 16;

  f32x4 zero = {0.f, 0.f, 0.f, 0.f};
  f32x4 acc[2][2];
  acc[0][0] = zero; acc[0][1] = zero; acc[1][0] = zero; acc[1][1] = zero;

#define FRAG(buf, t4, row, g) \
  (*(const f16x8*)&lds[buf][t4][(row) * 64 + ((((g) ^ ((row) & 7))) * 8)])

  LOAD(0);
  STORE(0);
  __syncthreads();
  for (int t16 = 0; t16 < 16; t16++) {
    int buf = t16 & 1;
    if (t16 < 15) LOAD(t16 + 1);  // in flight during MFMAs below
    #pragma unroll
    for (int ks = 0; ks < 2; ks++) {
      int gk = ks * 4 + rowg;
      f16x8 ah0 = FRAG(buf, 0, ma0, gk), ah1 = FRAG(buf, 0, ma1, gk);
      f16x8 al0 = FRAG(buf, 1, ma0, gk), al1 = FRAG(buf, 1, ma1, gk);
      f16x8 bh0 = FRAG(buf, 2, mb0, gk), bh1 = FRAG(buf, 2, mb1, gk);
      f16x8 bl0 = FRAG(buf, 3, mb0, gk), bl1 = FRAG(buf, 3, mb1, gk);
      acc[0][0] = __builtin_amdgcn_mfma_f32_16x16x32_f16(ah0, bh0, acc[0][0], 0, 0, 0);
      acc[0][0] = __builtin_amdgcn_mfma_f32_16x16x32_f16(ah0, bl0, acc[0][0], 0, 0, 0);
      acc[0][0] = __builtin_amdgcn_mfma_f32_16x16x32_f16(al0, bh0, acc[0][0], 0, 0, 0);
      acc[0][1] = __builtin_amdgcn_mfma_f32_16x16x32_f16(ah0, bh1, acc[0][1], 0, 0, 0);
      acc[0][1] = __builtin_amdgcn_mfma_f32_16x16x32_f16(ah0, bl1, acc[0][1], 0, 0, 0);
      acc[0][1] = __builtin_amdgcn_mfma_f32_16x16x32_f16(al0, bh1, acc[0][1], 0, 0, 0);
      acc[1][0] = __builtin_amdgcn_mfma_f32_16x16x32_f16(ah1, bh0, acc[1][0], 0, 0, 0);
      acc[1][0] = __builtin_amdgcn_mfma_f32_16x16x32_f16(ah1, bl0, acc[1][0], 0, 0, 0);
      acc[1][0] = __builtin_amdgcn_mfma_f32_16x16x32_f16(al1, bh0, acc[1][0], 0, 0, 0);
      acc[1][1] = __builtin_amdgcn_mfma_f32_16x16x32_f16(ah1, bh1, acc[1][1], 0, 0, 0);
      acc[1][1] = __builtin_amdgcn_mfma_f32_16x16x32_f16(ah1, bl1, acc[1][1], 0, 0, 0);
      acc[1][1] = __builtin_amdgcn_mfma_f32_16x16x32_f16(al1, bh1, acc[1][1], 0, 0, 0);
    }
    if (t16 < 15) {
      __syncthreads();
      STORE(buf ^ 1);
      __syncthreads();
    }
  }
#undef FRAG

  #pragma unroll
  for (int mi = 0; mi < 2; mi++) {
    #pragma unroll
    for (int i = 0; i < 4; i++) {
      int grow = bi * 64 + wr * 32 + mi * 16 + rowg * 4 + i;
      u64 key = 0;
      #pragma unroll
      for (int ni = 0; ni < 2; ni++) {
        int gcol = bj * 64 + wc * 32 + ni * 16 + colg;
        if (gcol < n2) {
          u64 k2 = packKey(acc[mi][ni][i], gcol);
          if (k2 > key) key = k2;
        }
      }
      #pragma unroll
      for (int m = 8; m; m >>= 1) {
        u64 o = (u64)__shfl_xor((long long)key, m, 64);
        if (o > key) key = o;
      }
      if (colg == 0 && grow < mid && key) atomicMax(&ws->bestKey[grow], key);
    }
  }
}

// ===== decode matches + residual compaction (verbatim r7) =====
__global__ __launch_bounds__(1024) void k_match(WS* ws) {
  __shared__ int flag[N];
  __shared__ int wsum[16];
  int tid = threadIdx.x;
  int lane = tid & 63, wv = tid >> 6;
  int mid = ws->mid, n2 = ws->n2;
  #pragma unroll
  for (int q = 0; q < 4; q++) flag[tid * 4 + q] = 0;
  __syncthreads();
  #pragma unroll
  for (int q = 0; q < 2; q++) {
    int r = tid + q * 1024;
    if (r < mid) {
      int j = (int)(~(unsigned)(ws->bestKey[r] & 0xffffffffull));
      ws->matches[r] = j;
      flag[j] = 1;  // benign race: same value
    }
  }
  __syncthreads();
  int v[4], loc[4]; int tot = 0;
  #pragma unroll
  for (int q = 0; q < 4; q++) {
    int j = tid * 4 + q;
    bool val = (j < n2) && (flag[j] == 0);
    v[q] = val; loc[q] = tot; tot += (int)val;
  }
  int inc = tot;
  #pragma unroll
  for (int o = 1; o < 64; o <<= 1) { int u = __shfl_up(inc, o, 64); if (lane >= o) inc += u; }
  if (lane == 63) wsum[wv] = inc;
  __syncthreads();
  if (tid < 16) {
    int t = wsum[tid];
    #pragma unroll
    for (int o = 1; o < 16; o <<= 1) { int u = __shfl_up(t, o, 64); if (tid >= o) t += u; }
    wsum[tid] = t;
  }
  __syncthreads();
  int base = (wv ? wsum[wv - 1] : 0) + inc - tot;
  #pragma unroll
  for (int q = 0; q < 4; q++)
    if (v[q]) ws->residIdx[base + loc[q]] = ws->A2idx[tid * 4 + q];
  if (tid == 0) ws->n_resid = wsum[15];
}

// ===== one block per output row (verbatim r7) =====
__global__ __launch_bounds__(256) void k_write(const float* __restrict__ x,
                                               float* __restrict__ out, WS* ws) {
  int r = blockIdx.x;
  int t = threadIdx.x;
  int n_B = ws->n_B, mid = ws->mid, n_resid = ws->n_resid;
  float4 res = make_float4(0.f, 0.f, 0.f, 0.f);
  if (r < N) {
    if (r < n_B) {
      res = ((const float4*)(x + (size_t)ws->Bidx[r] * D))[t];
    } else if (r < n_B + mid) {
      int m = r - n_B;
      float4 v1 = ((const float4*)(x + (size_t)ws->A1idx[m] * D))[t];
      float4 v2 = ((const float4*)(x + (size_t)ws->A2idx[ws->matches[m]] * D))[t];
      res = make_float4(0.5f * (v1.x + v2.x), 0.5f * (v1.y + v2.y),
                        0.5f * (v1.z + v2.z), 0.5f * (v1.w + v2.w));
    }
  } else {
    int k = r - N;
    if (k < n_resid) {
      res = ((const float4*)(x + (size_t)ws->residIdx[k] * D))[t];
    }
  }
  ((float4*)(out + (size_t)r * D))[t] = res;
}

extern "C" void kernel_launch(void* const* d_in, const int* in_sizes, int n_in,
                              void* d_out, int out_size, void* d_ws, size_t ws_size,
                              hipStream_t stream) {
  const float* x = (const float*)d_in[0];
  const float* attn = (const float*)d_in[1];
  float* out = (float*)d_out;
  WS* ws = (WS*)d_ws;
  // d_out (33.5 MB) doubles as scratch for the tiled packed f16 planes (16 MB);
  // k_write fully overwrites it afterwards (stream-ordered, deterministic).
  f16* PAhi = (f16*)d_out;
  f16* PAlo = PAhi + PLANE;
  f16* PBhi = PAlo + PLANE;
  f16* PBlo = PBhi + PLANE;

  k_prep<<<N, 256, 0, stream>>>(x, attn, ws);
  k_mask<<<1, 256, 0, stream>>>(ws);
  k_pack<<<4096, 128, 0, stream>>>(x, PAhi, PAlo, PBhi, PBlo, ws);
  k_gemm<<<256, 256, 0, stream>>>(PAhi, PAlo, PBhi, PBlo, ws);
  k_match<<<1, 1024, 0, stream>>>(ws);
  k_write<<<2 * N, 256, 0, stream>>>(x, out, ws);
}